// Round 6
// baseline (2635.790 us; speedup 1.0000x reference)
//
#include <hip/hip_runtime.h>
#include <hip/hip_bf16.h>

#define EPS 1e-5f

typedef __attribute__((ext_vector_type(8))) short short8;
typedef __attribute__((ext_vector_type(4))) float floatx4;
typedef __attribute__((ext_vector_type(2))) float f32x2;

static __device__ __forceinline__ short f2bf(float f) {
    __hip_bfloat16 h = __float2bfloat16(f);
    return *reinterpret_cast<short*>(&h);
}

// ---------------------------------------------------------------------------
// Kernel 0: prep — transpose+convert w2,w3 to bf16, zero the max-pool buffer
// ---------------------------------------------------------------------------
__global__ __launch_bounds__(256) void prep_kernel(const float* __restrict__ w2,
                                                   const float* __restrict__ w3,
                                                   short* __restrict__ w2T,
                                                   short* __restrict__ w3T,
                                                   int* __restrict__ gmax) {
    int i = blockIdx.x * 256 + threadIdx.x;   // grid 256 -> 65536 threads
    if (i < 8192) {                 // w2: [64][128] -> w2T[128][64]
        int k = i >> 7, n = i & 127;
        w2T[n * 64 + k] = f2bf(w2[i]);
    } else if (i < 40960) {         // w3: [128][256] -> w3T[256][128]
        int j = i - 8192;
        int k = j >> 8, n = j & 255;
        w3T[n * 128 + k] = f2bf(w3[j]);
    }
    if (i < 256 * 256) gmax[i] = 0; // float 0.0f bits
}

// ---------------------------------------------------------------------------
// Kernel 1: farthest point sampling. One block (1024 thr) per batch.
// 8 points/thread in registers (f32x2 pairs); coords staged in LDS for the
// per-step centroid broadcast; sampled output buffered in LDS, flushed at end.
// R6: distance core forced to packed fp32 via inline asm (v_pk_add_f32 /
// v_pk_mul_f32, 2 points per instr). Subtraction realized as x + (-c) with
// the negated centroid hoisted per step — bit-identical to x - c in IEEE,
// so the exact numpy ordering (dx*dx + dy*dy) + dz*dz is preserved.
// Argmax key: u64 (dist_bits<<32 | 8191-idx); 6-step DPP wave max-reduce,
// lane 63 -> ds_max_u64 into a 3-slot rotating LDS cell. ONE barrier/step.
// ---------------------------------------------------------------------------
#define DPP_MAXU64(pk, CTRL, RM)                                             \
    {                                                                        \
        int lo_ = (int)(unsigned)((pk) & 0xffffffffull);                     \
        int hi_ = (int)(unsigned)((pk) >> 32);                               \
        int nlo_ = __builtin_amdgcn_update_dpp(lo_, lo_, CTRL, RM, 0xf, false); \
        int nhi_ = __builtin_amdgcn_update_dpp(hi_, hi_, CTRL, RM, 0xf, false); \
        unsigned long long o_ =                                              \
            ((unsigned long long)(unsigned)nhi_ << 32) | (unsigned)nlo_;     \
        if (o_ > (pk)) (pk) = o_;                                            \
    }

#define PK_ADD(d, a, b) asm("v_pk_add_f32 %0, %1, %2" : "=v"(d) : "v"(a), "v"(b))
#define PK_MUL(d, a, b) asm("v_pk_mul_f32 %0, %1, %2" : "=v"(d) : "v"(a), "v"(b))

__global__ __launch_bounds__(1024, 4) void fps_kernel(const float* __restrict__ pc,
                                                      float* __restrict__ sampled) {
#pragma clang fp contract(off)
    const int b = blockIdx.x;
    const int tid = threadIdx.x;
    const int lane = tid & 63;
    const float* __restrict__ P = pc + (size_t)b * 8192 * 3;
    float* __restrict__ outp = sampled + (size_t)b * 2048 * 3;

    __shared__ float sx[8192];
    __shared__ float sy[8192];
    __shared__ float sz[8192];
    __shared__ float sout[2048 * 3];
    __shared__ unsigned long long slots[3];

    // stage coords: global -> registers (pairs) and LDS
    f32x2 px2[4], py2[4], pz2[4], d2[4];
#pragma unroll
    for (int j = 0; j < 4; ++j) {
        int i0 = j * 2048 + tid;           // lo half (smaller idx)
        int i1 = j * 2048 + 1024 + tid;    // hi half
        float x0 = P[i0 * 3 + 0], y0 = P[i0 * 3 + 1], z0 = P[i0 * 3 + 2];
        float x1 = P[i1 * 3 + 0], y1 = P[i1 * 3 + 1], z1 = P[i1 * 3 + 2];
        px2[j][0] = x0; px2[j][1] = x1;
        py2[j][0] = y0; py2[j][1] = y1;
        pz2[j][0] = z0; pz2[j][1] = z1;
        d2[j][0] = INFINITY; d2[j][1] = INFINITY;
        sx[i0] = x0; sy[i0] = y0; sz[i0] = z0;
        sx[i1] = x1; sy[i1] = y1; sz[i1] = z1;
    }
    if (tid < 3) slots[tid] = 0ull;
    const int tid_hi = tid + 1024;
    __syncthreads();

    int far = 0;
    int p = 0;   // = s % 3
    for (int s = 0; s < 2048; ++s) {
        const float cx = sx[far];
        const float cy = sy[far];
        const float cz = sz[far];
        if (tid == 0) {
            sout[s * 3 + 0] = cx;
            sout[s * 3 + 1] = cy;
            sout[s * 3 + 2] = cz;
        }
        if (s == 2047) break;

        // negated centroid, hoisted: x - c == x + (-c) exactly (IEEE)
        const f32x2 nc2x = {-cx, -cx}, nc2y = {-cy, -cy}, nc2z = {-cz, -cz};
        float bv_lo = -1.0f, bv_hi = -1.0f;
        int bj_lo = 0, bj_hi = 0;
#pragma unroll
        for (int j = 0; j < 4; ++j) {
            f32x2 dx, dy, dz, xx, yy, zz, s1, dd;
            PK_ADD(dx, px2[j], nc2x);
            PK_ADD(dy, py2[j], nc2y);
            PK_ADD(dz, pz2[j], nc2z);
            PK_MUL(xx, dx, dx);
            PK_MUL(yy, dy, dy);
            PK_MUL(zz, dz, dz);
            PK_ADD(s1, xx, yy);       // dx*dx + dy*dy
            PK_ADD(dd, s1, zz);       // (dx*dx + dy*dy) + dz*dz — numpy order
            float nd0 = fminf(d2[j][0], dd[0]);
            float nd1 = fminf(d2[j][1], dd[1]);
            d2[j][0] = nd0;
            d2[j][1] = nd1;
            // branch-free argmax tracking: cmp + cndmask + max
            bj_lo = (nd0 > bv_lo) ? j : bj_lo;
            bj_hi = (nd1 > bv_hi) ? j : bj_hi;
            bv_lo = fmaxf(bv_lo, nd0);
            bv_hi = fmaxf(bv_hi, nd1);
        }
        // merge halves (lo has smaller global idx -> keep lo on tie)
        bool ch = bv_hi > bv_lo;
        float bv = fmaxf(bv_lo, bv_hi);
        int bi_lo = (bj_lo << 11) + tid;      // j*2048 + tid
        int bi_hi = (bj_hi << 11) + tid_hi;   // j*2048 + 1024 + tid
        int bi = ch ? bi_hi : bi_lo;

        // pack: max value, then min index (8191-idx grows as idx shrinks)
        unsigned long long pk =
            ((unsigned long long)__float_as_uint(bv) << 32) | (unsigned)(8191 - bi);

        // 6-step DPP wave max-reduce -> lane 63 holds the wave max
        DPP_MAXU64(pk, 0x111, 0xf);  // row_shr:1
        DPP_MAXU64(pk, 0x112, 0xf);  // row_shr:2
        DPP_MAXU64(pk, 0x114, 0xf);  // row_shr:4
        DPP_MAXU64(pk, 0x118, 0xf);  // row_shr:8
        DPP_MAXU64(pk, 0x142, 0xa);  // row_bcast15 -> rows 1,3
        DPP_MAXU64(pk, 0x143, 0xc);  // row_bcast31 -> rows 2,3

        if (lane == 63)
            atomicMax(&slots[p], pk);            // ds_max_u64, 16/step
        __syncthreads();

        unsigned long long best = slots[p];
        if (tid == 0)
            slots[p >= 1 ? p - 1 : 2] = 0ull;    // reset slot for step s+2
        far = 8191 - (int)(unsigned)(best & 0xFFFFFFFFull);
        p = (p == 2) ? 0 : p + 1;
    }

    __syncthreads();
#pragma unroll
    for (int i = 0; i < 6; ++i)
        outp[i * 1024 + tid] = sout[i * 1024 + tid];
}

// ---------------------------------------------------------------------------
// Kernel 2: fused per-point MLP (3->64->128->256, LN+ReLU each) + max-pool.
// Block = 256 thr (4 waves) handles 64 points of one batch.
// MFMA 16x16x32 bf16; LN stats via per-lane partials + LDS reduce.
// Fragment layouts (m89/m120 verified):
//   A[m][k]: m = lane&15, k = (lane>>4)*8 + j
//   B[k][n]: n = lane&15, k = (lane>>4)*8 + j
//   D[row][col]: col = lane&15, row = (lane>>4)*4 + reg
// ---------------------------------------------------------------------------
__global__ __launch_bounds__(256) void mlp_kernel(
    const float* __restrict__ sampled,
    const float* __restrict__ w1, const float* __restrict__ b1,
    const float* __restrict__ g1, const float* __restrict__ be1,
    const short* __restrict__ w2T, const float* __restrict__ b2,
    const float* __restrict__ g2, const float* __restrict__ be2,
    const short* __restrict__ w3T, const float* __restrict__ b3,
    const float* __restrict__ g3, const float* __restrict__ be3,
    int* __restrict__ gmax) {

    const int b = blockIdx.x >> 5;
    const int chunk = blockIdx.x & 31;
    const int tid = threadIdx.x;
    const int w = tid >> 6;        // wave 0..3
    const int lane = tid & 63;
    const int quad = lane >> 4;
    const int col = lane & 15;

    __shared__ __align__(16) short X1[64 * 72];          //  9216 B bf16 h1
    __shared__ __align__(16) char bufB[64 * 136 * 2];    // 17408 B: Y1(f32) then X2(bf16)
    __shared__ float statsS[64 * 65];                    // 16640 B
    __shared__ float statsQ[64 * 65];                    // 16640 B
    __shared__ float mean_s[64];
    __shared__ float inv_s[64];

    float* Y1 = reinterpret_cast<float*>(bufB);          // [64][65]
    short* X2 = reinterpret_cast<short*>(bufB);          // [64][136]

    // ---- preload B fragments (weights, bf16, transposed layout) ----
    short8 b2f[2][2];
#pragma unroll
    for (int nt = 0; nt < 2; ++nt)
#pragma unroll
        for (int ks = 0; ks < 2; ++ks)
            b2f[nt][ks] = *(const short8*)&w2T[((w * 2 + nt) * 16 + col) * 64 + ks * 32 + quad * 8];
    short8 b3f[4][4];
#pragma unroll
    for (int nt = 0; nt < 4; ++nt)
#pragma unroll
        for (int ks = 0; ks < 4; ++ks)
            b3f[nt][ks] = *(const short8*)&w3T[((w * 4 + nt) * 16 + col) * 128 + ks * 32 + quad * 8];

    // ---- layer 1 (VALU): 3 -> 64 ----
    const int pt = tid & 63;
    const int cg = (tid >> 6) * 16;
    const float* Pp = &sampled[((size_t)b * 2048 + chunk * 64 + pt) * 3];
    const float x = Pp[0], y = Pp[1], z = Pp[2];
#pragma unroll
    for (int c = 0; c < 16; ++c) {
        int ch = cg + c;
        Y1[pt * 65 + ch] = fmaf(x, w1[ch], fmaf(y, w1[64 + ch], fmaf(z, w1[128 + ch], b1[ch])));
    }
    __syncthreads();

    if (tid < 64) {
        float s = 0.f, q = 0.f;
        for (int k = 0; k < 64; ++k) {
            float v = Y1[tid * 65 + k];
            s += v; q += v * v;
        }
        float m = s * (1.f / 64.f);
        float var = q * (1.f / 64.f) - m * m;
        mean_s[tid] = m;
        inv_s[tid] = rsqrtf(var + EPS);
    }
    __syncthreads();

#pragma unroll
    for (int c = 0; c < 16; ++c) {
        int ch = cg + c;
        float v = (Y1[pt * 65 + ch] - mean_s[pt]) * inv_s[pt] * g1[ch] + be1[ch];
        X1[pt * 72 + ch] = f2bf(fmaxf(v, 0.f));
    }
    __syncthreads();

    // ---- layer 2 (MFMA): 64 -> 128 ----
    const floatx4 zf = {0.f, 0.f, 0.f, 0.f};
    floatx4 acc2[4][2];
#pragma unroll
    for (int mt = 0; mt < 4; ++mt) {
        acc2[mt][0] = zf; acc2[mt][1] = zf;
        short8 a[2];
#pragma unroll
        for (int ks = 0; ks < 2; ++ks)
            a[ks] = *(const short8*)&X1[(mt * 16 + col) * 72 + ks * 32 + quad * 8];
#pragma unroll
        for (int nt = 0; nt < 2; ++nt)
#pragma unroll
            for (int ks = 0; ks < 2; ++ks)
                acc2[mt][nt] = __builtin_amdgcn_mfma_f32_16x16x32_bf16(a[ks], b2f[nt][ks], acc2[mt][nt], 0, 0, 0);
    }
    int ch2[2];
    float b2v[2], g2v[2], be2v[2];
#pragma unroll
    for (int nt = 0; nt < 2; ++nt) {
        ch2[nt] = (w * 2 + nt) * 16 + col;
        b2v[nt] = b2[ch2[nt]]; g2v[nt] = g2[ch2[nt]]; be2v[nt] = be2[ch2[nt]];
    }
#pragma unroll
    for (int mt = 0; mt < 4; ++mt)
#pragma unroll
        for (int r = 0; r < 4; ++r) {
            float v0 = acc2[mt][0][r] + b2v[0];
            float v1 = acc2[mt][1][r] + b2v[1];
            acc2[mt][0][r] = v0; acc2[mt][1][r] = v1;
            int p = mt * 16 + quad * 4 + r;
            statsS[p * 65 + w * 16 + col] = v0 + v1;
            statsQ[p * 65 + w * 16 + col] = v0 * v0 + v1 * v1;
        }
    __syncthreads();
    if (tid < 64) {
        float s = 0.f, q = 0.f;
        for (int k = 0; k < 64; ++k) { s += statsS[tid * 65 + k]; q += statsQ[tid * 65 + k]; }
        float m = s * (1.f / 128.f);
        float var = q * (1.f / 128.f) - m * m;
        mean_s[tid] = m;
        inv_s[tid] = rsqrtf(var + EPS);
    }
    __syncthreads();
#pragma unroll
    for (int mt = 0; mt < 4; ++mt)
#pragma unroll
        for (int r = 0; r < 4; ++r) {
            int p = mt * 16 + quad * 4 + r;
            float m = mean_s[p], iv = inv_s[p];
#pragma unroll
            for (int nt = 0; nt < 2; ++nt) {
                float v = (acc2[mt][nt][r] - m) * iv * g2v[nt] + be2v[nt];
                X2[p * 136 + ch2[nt]] = f2bf(fmaxf(v, 0.f));
            }
        }
    __syncthreads();

    // ---- layer 3 (MFMA): 128 -> 256 ----
    floatx4 acc3[4][4];
#pragma unroll
    for (int mt = 0; mt < 4; ++mt) {
#pragma unroll
        for (int nt = 0; nt < 4; ++nt) acc3[mt][nt] = zf;
        short8 a[4];
#pragma unroll
        for (int ks = 0; ks < 4; ++ks)
            a[ks] = *(const short8*)&X2[(mt * 16 + col) * 136 + ks * 32 + quad * 8];
#pragma unroll
        for (int nt = 0; nt < 4; ++nt)
#pragma unroll
            for (int ks = 0; ks < 4; ++ks)
                acc3[mt][nt] = __builtin_amdgcn_mfma_f32_16x16x32_bf16(a[ks], b3f[nt][ks], acc3[mt][nt], 0, 0, 0);
    }
    int ch3[4];
    float b3v[4], g3v[4], be3v[4];
#pragma unroll
    for (int nt = 0; nt < 4; ++nt) {
        ch3[nt] = (w * 4 + nt) * 16 + col;
        b3v[nt] = b3[ch3[nt]]; g3v[nt] = g3[ch3[nt]]; be3v[nt] = be3[ch3[nt]];
    }
#pragma unroll
    for (int mt = 0; mt < 4; ++mt)
#pragma unroll
        for (int r = 0; r < 4; ++r) {
            float s = 0.f, q = 0.f;
#pragma unroll
            for (int nt = 0; nt < 4; ++nt) {
                float v = acc3[mt][nt][r] + b3v[nt];
                acc3[mt][nt][r] = v;
                s += v; q += v * v;
            }
            int p = mt * 16 + quad * 4 + r;
            statsS[p * 65 + w * 16 + col] = s;
            statsQ[p * 65 + w * 16 + col] = q;
        }
    __syncthreads();
    if (tid < 64) {
        float s = 0.f, q = 0.f;
        for (int k = 0; k < 64; ++k) { s += statsS[tid * 65 + k]; q += statsQ[tid * 65 + k]; }
        float m = s * (1.f / 256.f);
        float var = q * (1.f / 256.f) - m * m;
        mean_s[tid] = m;
        inv_s[tid] = rsqrtf(var + EPS);
    }
    __syncthreads();

    // ---- LN3 + ReLU + max over the block's 64 points ----
    float mx[4] = {0.f, 0.f, 0.f, 0.f};
#pragma unroll
    for (int mt = 0; mt < 4; ++mt)
#pragma unroll
        for (int r = 0; r < 4; ++r) {
            int p = mt * 16 + quad * 4 + r;
            float m = mean_s[p], iv = inv_s[p];
#pragma unroll
            for (int nt = 0; nt < 4; ++nt) {
                float v = (acc3[mt][nt][r] - m) * iv * g3v[nt] + be3v[nt];
                mx[nt] = fmaxf(mx[nt], fmaxf(v, 0.f));
            }
        }
#pragma unroll
    for (int nt = 0; nt < 4; ++nt) {
        float m = mx[nt];
        m = fmaxf(m, __shfl_xor(m, 16));
        m = fmaxf(m, __shfl_xor(m, 32));
        if (lane < 16)  // quad==0 lanes cover cols 0..15
            atomicMax(&gmax[b * 256 + ch3[nt]], __float_as_int(m));
    }
}

// ---------------------------------------------------------------------------
// Kernel 3: heads. One wave per batch row (fp32 exact).
// ---------------------------------------------------------------------------
__global__ __launch_bounds__(64) void final_kernel(
    const float* __restrict__ g, const float* __restrict__ js,
    const float* __restrict__ wp, const float* __restrict__ bp,
    const float* __restrict__ gp, const float* __restrict__ bep,
    const float* __restrict__ ws1, const float* __restrict__ bs1,
    const float* __restrict__ ws2, const float* __restrict__ bs2,
    float* __restrict__ out) {
    const int b = blockIdx.x;
    const int c = threadIdx.x;   // 0..63

    // global token = LN(g @ wp + bp) * gp + bep
    const float* grow = g + b * 256;
    float acc = bp[c];
    for (int k = 0; k < 256; ++k) acc = fmaf(grow[k], wp[k * 64 + c], acc);
    float s = acc;
#pragma unroll
    for (int m = 1; m < 64; m <<= 1) s += __shfl_xor(s, m);
    float mean = s * (1.f / 64.f);
    float dc = acc - mean;
    float q = dc * dc;
#pragma unroll
    for (int m = 1; m < 64; m <<= 1) q += __shfl_xor(q, m);
    float var = q * (1.f / 64.f);
    out[b * 128 + c] = dc * rsqrtf(var + EPS) * gp[c] + bep[c];

    // joint-state branch
    const float* jrow = js + b * 32;
    float h = bs1[c];
    for (int k = 0; k < 32; ++k) h = fmaf(jrow[k], ws1[k * 64 + c], h);
    h = fmaxf(h, 0.f);
    float s2 = bs2[c];
    for (int k = 0; k < 64; ++k) s2 = fmaf(__shfl(h, k), ws2[k * 64 + c], s2);
    out[b * 128 + 64 + c] = s2;
}

// ---------------------------------------------------------------------------
extern "C" void kernel_launch(void* const* d_in, const int* in_sizes, int n_in,
                              void* d_out, int out_size, void* d_ws, size_t ws_size,
                              hipStream_t stream) {
    const float* pc  = (const float*)d_in[0];   // (256, 8192, 3)
    const float* js  = (const float*)d_in[1];   // (256, 32)
    // d_in[2] = num_points (2048, fixed by setup — hardcoded)
    const float* w1  = (const float*)d_in[3];
    const float* b1  = (const float*)d_in[4];
    const float* g1  = (const float*)d_in[5];
    const float* be1 = (const float*)d_in[6];
    const float* w2  = (const float*)d_in[7];
    const float* b2  = (const float*)d_in[8];
    const float* g2  = (const float*)d_in[9];
    const float* be2 = (const float*)d_in[10];
    const float* w3  = (const float*)d_in[11];
    const float* b3  = (const float*)d_in[12];
    const float* g3  = (const float*)d_in[13];
    const float* be3 = (const float*)d_in[14];
    const float* wp  = (const float*)d_in[15];
    const float* bp  = (const float*)d_in[16];
    const float* gp  = (const float*)d_in[17];
    const float* bep = (const float*)d_in[18];
    const float* ws1 = (const float*)d_in[19];
    const float* bs1 = (const float*)d_in[20];
    const float* ws2 = (const float*)d_in[21];
    const float* bs2 = (const float*)d_in[22];

    char* ws = (char*)d_ws;
    float* sampled = (float*)(ws + 0);               // 256*2048*3 f32 = 6291456 B
    int*   gmax    = (int*)(ws + 6291456);           // 256*256 i32   =  262144 B
    short* w2T     = (short*)(ws + 6553600);         // 128*64 bf16   =   16384 B
    short* w3T     = (short*)(ws + 6569984);         // 256*128 bf16  =   65536 B

    prep_kernel<<<256, 256, 0, stream>>>(w2, w3, w2T, w3T, gmax);
    fps_kernel<<<256, 1024, 0, stream>>>(pc, sampled);
    mlp_kernel<<<8192, 256, 0, stream>>>(sampled, w1, b1, g1, be1,
                                         w2T, b2, g2, be2, w3T, b3, g3, be3, gmax);
    final_kernel<<<256, 64, 0, stream>>>((const float*)gmax, js, wp, bp, gp, bep,
                                         ws1, bs1, ws2, bs2, (float*)d_out);
}

// Round 7
// 2289.599 us; speedup vs baseline: 1.1512x; 1.1512x over previous
//
#include <hip/hip_runtime.h>
#include <hip/hip_bf16.h>

#define EPS 1e-5f

typedef __attribute__((ext_vector_type(8))) short short8;
typedef __attribute__((ext_vector_type(4))) float floatx4;

static __device__ __forceinline__ short f2bf(float f) {
    __hip_bfloat16 h = __float2bfloat16(f);
    return *reinterpret_cast<short*>(&h);
}

// ---------------------------------------------------------------------------
// Kernel 0: prep — transpose+convert w2,w3 to bf16, zero the max-pool buffer
// ---------------------------------------------------------------------------
__global__ __launch_bounds__(256) void prep_kernel(const float* __restrict__ w2,
                                                   const float* __restrict__ w3,
                                                   short* __restrict__ w2T,
                                                   short* __restrict__ w3T,
                                                   int* __restrict__ gmax) {
    int i = blockIdx.x * 256 + threadIdx.x;   // grid 256 -> 65536 threads
    if (i < 8192) {                 // w2: [64][128] -> w2T[128][64]
        int k = i >> 7, n = i & 127;
        w2T[n * 64 + k] = f2bf(w2[i]);
    } else if (i < 40960) {         // w3: [128][256] -> w3T[256][128]
        int j = i - 8192;
        int k = j >> 8, n = j & 255;
        w3T[n * 128 + k] = f2bf(w3[j]);
    }
    if (i < 256 * 256) gmax[i] = 0; // float 0.0f bits
}

// ---------------------------------------------------------------------------
// Kernel 1: farthest point sampling. One block (256 thr = 4 waves, ONE wave
// per SIMD) per batch. 32 points/thread in scalar register arrays (~128
// VGPRs; __launch_bounds__(256,1) -> 512-VGPR budget, no spill).
// R7 rationale: R4/R5/R6 showed step time pinned at ~2900 cyc regardless of
// update-loop form -> per-wave overhead (reduce/bookkeeping ~80 instrs) paid
// x16 waves + 16-wave barrier was the invariant. 4 waves pays it x4, syncs
// x4, and the 32-pt unrolled loop has high ILP for single-wave issue.
// Coords staged in LDS for the centroid broadcast; sampled output buffered
// in LDS, flushed at end. Argmax key: u64 (dist_bits<<32 | 8191-idx);
// 6-step DPP wave max-reduce; lane 63 -> ds_max_u64 into a 3-slot rotating
// LDS cell. ONE barrier/step. Exact fp32, contraction off, numpy op order.
// ---------------------------------------------------------------------------
#define DPP_MAXU64(pk, CTRL, RM)                                             \
    {                                                                        \
        int lo_ = (int)(unsigned)((pk) & 0xffffffffull);                     \
        int hi_ = (int)(unsigned)((pk) >> 32);                               \
        int nlo_ = __builtin_amdgcn_update_dpp(lo_, lo_, CTRL, RM, 0xf, false); \
        int nhi_ = __builtin_amdgcn_update_dpp(hi_, hi_, CTRL, RM, 0xf, false); \
        unsigned long long o_ =                                              \
            ((unsigned long long)(unsigned)nhi_ << 32) | (unsigned)nlo_;     \
        if (o_ > (pk)) (pk) = o_;                                            \
    }

__global__ __launch_bounds__(256, 1) void fps_kernel(const float* __restrict__ pc,
                                                     float* __restrict__ sampled) {
#pragma clang fp contract(off)
    const int b = blockIdx.x;
    const int tid = threadIdx.x;   // 0..255
    const int lane = tid & 63;
    const float* __restrict__ P = pc + (size_t)b * 8192 * 3;
    float* __restrict__ outp = sampled + (size_t)b * 2048 * 3;

    __shared__ float sx[8192];
    __shared__ float sy[8192];
    __shared__ float sz[8192];
    __shared__ float sout[2048 * 3];
    __shared__ unsigned long long slots[3];

    // stage coords: global -> registers and LDS. thread owns points j*256+tid
    float px[32], py[32], pz[32], d[32];
#pragma unroll
    for (int j = 0; j < 32; ++j) {
        int i0 = j * 256 + tid;
        float x0 = P[i0 * 3 + 0], y0 = P[i0 * 3 + 1], z0 = P[i0 * 3 + 2];
        px[j] = x0; py[j] = y0; pz[j] = z0;
        d[j] = INFINITY;
        sx[i0] = x0; sy[i0] = y0; sz[i0] = z0;
    }
    if (tid < 3) slots[tid] = 0ull;
    __syncthreads();

    int far = 0;
    int p = 0;   // = s % 3
    for (int s = 0; s < 2048; ++s) {
        const float cx = sx[far];
        const float cy = sy[far];
        const float cz = sz[far];
        if (tid == 0) {
            sout[s * 3 + 0] = cx;
            sout[s * 3 + 1] = cy;
            sout[s * 3 + 2] = cz;
        }
        if (s == 2047) break;

        float bv = -1.0f;
        int bj = 0;
#pragma unroll
        for (int j = 0; j < 32; ++j) {
            float dx = px[j] - cx;
            float dy = py[j] - cy;
            float dz = pz[j] - cz;
            // exact numpy order: (dx*dx + dy*dy) + dz*dz, contraction OFF
            float dd = (dx * dx + dy * dy) + dz * dz;
            float nd = fminf(d[j], dd);
            d[j] = nd;
            // strict > keeps smallest j on ties -> smallest global index
            bj = (nd > bv) ? j : bj;
            bv = fmaxf(bv, nd);
        }
        int bi = (bj << 8) + tid;

        // pack: max value, then min index (8191-idx grows as idx shrinks)
        unsigned long long pk =
            ((unsigned long long)__float_as_uint(bv) << 32) | (unsigned)(8191 - bi);

        // 6-step DPP wave max-reduce -> lane 63 holds the wave max
        DPP_MAXU64(pk, 0x111, 0xf);  // row_shr:1
        DPP_MAXU64(pk, 0x112, 0xf);  // row_shr:2
        DPP_MAXU64(pk, 0x114, 0xf);  // row_shr:4
        DPP_MAXU64(pk, 0x118, 0xf);  // row_shr:8
        DPP_MAXU64(pk, 0x142, 0xa);  // row_bcast15 -> rows 1,3
        DPP_MAXU64(pk, 0x143, 0xc);  // row_bcast31 -> rows 2,3

        if (lane == 63)
            atomicMax(&slots[p], pk);            // ds_max_u64, 4/step
        __syncthreads();

        unsigned long long best = slots[p];
        if (tid == 0)
            slots[p >= 1 ? p - 1 : 2] = 0ull;    // reset slot for step s+2
        far = 8191 - (int)(unsigned)(best & 0xFFFFFFFFull);
        p = (p == 2) ? 0 : p + 1;
    }

    __syncthreads();
#pragma unroll
    for (int i = 0; i < 24; ++i)
        outp[i * 256 + tid] = sout[i * 256 + tid];
}

// ---------------------------------------------------------------------------
// Kernel 2: fused per-point MLP (3->64->128->256, LN+ReLU each) + max-pool.
// Block = 256 thr (4 waves) handles 64 points of one batch.
// MFMA 16x16x32 bf16; LN stats via per-lane partials + LDS reduce.
// Fragment layouts (m89/m120 verified):
//   A[m][k]: m = lane&15, k = (lane>>4)*8 + j
//   B[k][n]: n = lane&15, k = (lane>>4)*8 + j
//   D[row][col]: col = lane&15, row = (lane>>4)*4 + reg
// ---------------------------------------------------------------------------
__global__ __launch_bounds__(256) void mlp_kernel(
    const float* __restrict__ sampled,
    const float* __restrict__ w1, const float* __restrict__ b1,
    const float* __restrict__ g1, const float* __restrict__ be1,
    const short* __restrict__ w2T, const float* __restrict__ b2,
    const float* __restrict__ g2, const float* __restrict__ be2,
    const short* __restrict__ w3T, const float* __restrict__ b3,
    const float* __restrict__ g3, const float* __restrict__ be3,
    int* __restrict__ gmax) {

    const int b = blockIdx.x >> 5;
    const int chunk = blockIdx.x & 31;
    const int tid = threadIdx.x;
    const int w = tid >> 6;        // wave 0..3
    const int lane = tid & 63;
    const int quad = lane >> 4;
    const int col = lane & 15;

    __shared__ __align__(16) short X1[64 * 72];          //  9216 B bf16 h1
    __shared__ __align__(16) char bufB[64 * 136 * 2];    // 17408 B: Y1(f32) then X2(bf16)
    __shared__ float statsS[64 * 65];                    // 16640 B
    __shared__ float statsQ[64 * 65];                    // 16640 B
    __shared__ float mean_s[64];
    __shared__ float inv_s[64];

    float* Y1 = reinterpret_cast<float*>(bufB);          // [64][65]
    short* X2 = reinterpret_cast<short*>(bufB);          // [64][136]

    // ---- preload B fragments (weights, bf16, transposed layout) ----
    short8 b2f[2][2];
#pragma unroll
    for (int nt = 0; nt < 2; ++nt)
#pragma unroll
        for (int ks = 0; ks < 2; ++ks)
            b2f[nt][ks] = *(const short8*)&w2T[((w * 2 + nt) * 16 + col) * 64 + ks * 32 + quad * 8];
    short8 b3f[4][4];
#pragma unroll
    for (int nt = 0; nt < 4; ++nt)
#pragma unroll
        for (int ks = 0; ks < 4; ++ks)
            b3f[nt][ks] = *(const short8*)&w3T[((w * 4 + nt) * 16 + col) * 128 + ks * 32 + quad * 8];

    // ---- layer 1 (VALU): 3 -> 64 ----
    const int pt = tid & 63;
    const int cg = (tid >> 6) * 16;
    const float* Pp = &sampled[((size_t)b * 2048 + chunk * 64 + pt) * 3];
    const float x = Pp[0], y = Pp[1], z = Pp[2];
#pragma unroll
    for (int c = 0; c < 16; ++c) {
        int ch = cg + c;
        Y1[pt * 65 + ch] = fmaf(x, w1[ch], fmaf(y, w1[64 + ch], fmaf(z, w1[128 + ch], b1[ch])));
    }
    __syncthreads();

    if (tid < 64) {
        float s = 0.f, q = 0.f;
        for (int k = 0; k < 64; ++k) {
            float v = Y1[tid * 65 + k];
            s += v; q += v * v;
        }
        float m = s * (1.f / 64.f);
        float var = q * (1.f / 64.f) - m * m;
        mean_s[tid] = m;
        inv_s[tid] = rsqrtf(var + EPS);
    }
    __syncthreads();

#pragma unroll
    for (int c = 0; c < 16; ++c) {
        int ch = cg + c;
        float v = (Y1[pt * 65 + ch] - mean_s[pt]) * inv_s[pt] * g1[ch] + be1[ch];
        X1[pt * 72 + ch] = f2bf(fmaxf(v, 0.f));
    }
    __syncthreads();

    // ---- layer 2 (MFMA): 64 -> 128 ----
    const floatx4 zf = {0.f, 0.f, 0.f, 0.f};
    floatx4 acc2[4][2];
#pragma unroll
    for (int mt = 0; mt < 4; ++mt) {
        acc2[mt][0] = zf; acc2[mt][1] = zf;
        short8 a[2];
#pragma unroll
        for (int ks = 0; ks < 2; ++ks)
            a[ks] = *(const short8*)&X1[(mt * 16 + col) * 72 + ks * 32 + quad * 8];
#pragma unroll
        for (int nt = 0; nt < 2; ++nt)
#pragma unroll
            for (int ks = 0; ks < 2; ++ks)
                acc2[mt][nt] = __builtin_amdgcn_mfma_f32_16x16x32_bf16(a[ks], b2f[nt][ks], acc2[mt][nt], 0, 0, 0);
    }
    int ch2[2];
    float b2v[2], g2v[2], be2v[2];
#pragma unroll
    for (int nt = 0; nt < 2; ++nt) {
        ch2[nt] = (w * 2 + nt) * 16 + col;
        b2v[nt] = b2[ch2[nt]]; g2v[nt] = g2[ch2[nt]]; be2v[nt] = be2[ch2[nt]];
    }
#pragma unroll
    for (int mt = 0; mt < 4; ++mt)
#pragma unroll
        for (int r = 0; r < 4; ++r) {
            float v0 = acc2[mt][0][r] + b2v[0];
            float v1 = acc2[mt][1][r] + b2v[1];
            acc2[mt][0][r] = v0; acc2[mt][1][r] = v1;
            int p = mt * 16 + quad * 4 + r;
            statsS[p * 65 + w * 16 + col] = v0 + v1;
            statsQ[p * 65 + w * 16 + col] = v0 * v0 + v1 * v1;
        }
    __syncthreads();
    if (tid < 64) {
        float s = 0.f, q = 0.f;
        for (int k = 0; k < 64; ++k) { s += statsS[tid * 65 + k]; q += statsQ[tid * 65 + k]; }
        float m = s * (1.f / 128.f);
        float var = q * (1.f / 128.f) - m * m;
        mean_s[tid] = m;
        inv_s[tid] = rsqrtf(var + EPS);
    }
    __syncthreads();
#pragma unroll
    for (int mt = 0; mt < 4; ++mt)
#pragma unroll
        for (int r = 0; r < 4; ++r) {
            int p = mt * 16 + quad * 4 + r;
            float m = mean_s[p], iv = inv_s[p];
#pragma unroll
            for (int nt = 0; nt < 2; ++nt) {
                float v = (acc2[mt][nt][r] - m) * iv * g2v[nt] + be2v[nt];
                X2[p * 136 + ch2[nt]] = f2bf(fmaxf(v, 0.f));
            }
        }
    __syncthreads();

    // ---- layer 3 (MFMA): 128 -> 256 ----
    floatx4 acc3[4][4];
#pragma unroll
    for (int mt = 0; mt < 4; ++mt) {
#pragma unroll
        for (int nt = 0; nt < 4; ++nt) acc3[mt][nt] = zf;
        short8 a[4];
#pragma unroll
        for (int ks = 0; ks < 4; ++ks)
            a[ks] = *(const short8*)&X2[(mt * 16 + col) * 136 + ks * 32 + quad * 8];
#pragma unroll
        for (int nt = 0; nt < 4; ++nt)
#pragma unroll
            for (int ks = 0; ks < 4; ++ks)
                acc3[mt][nt] = __builtin_amdgcn_mfma_f32_16x16x32_bf16(a[ks], b3f[nt][ks], acc3[mt][nt], 0, 0, 0);
    }
    int ch3[4];
    float b3v[4], g3v[4], be3v[4];
#pragma unroll
    for (int nt = 0; nt < 4; ++nt) {
        ch3[nt] = (w * 4 + nt) * 16 + col;
        b3v[nt] = b3[ch3[nt]]; g3v[nt] = g3[ch3[nt]]; be3v[nt] = be3[ch3[nt]];
    }
#pragma unroll
    for (int mt = 0; mt < 4; ++mt)
#pragma unroll
        for (int r = 0; r < 4; ++r) {
            float s = 0.f, q = 0.f;
#pragma unroll
            for (int nt = 0; nt < 4; ++nt) {
                float v = acc3[mt][nt][r] + b3v[nt];
                acc3[mt][nt][r] = v;
                s += v; q += v * v;
            }
            int p = mt * 16 + quad * 4 + r;
            statsS[p * 65 + w * 16 + col] = s;
            statsQ[p * 65 + w * 16 + col] = q;
        }
    __syncthreads();
    if (tid < 64) {
        float s = 0.f, q = 0.f;
        for (int k = 0; k < 64; ++k) { s += statsS[tid * 65 + k]; q += statsQ[tid * 65 + k]; }
        float m = s * (1.f / 256.f);
        float var = q * (1.f / 256.f) - m * m;
        mean_s[tid] = m;
        inv_s[tid] = rsqrtf(var + EPS);
    }
    __syncthreads();

    // ---- LN3 + ReLU + max over the block's 64 points ----
    float mx[4] = {0.f, 0.f, 0.f, 0.f};
#pragma unroll
    for (int mt = 0; mt < 4; ++mt)
#pragma unroll
        for (int r = 0; r < 4; ++r) {
            int p = mt * 16 + quad * 4 + r;
            float m = mean_s[p], iv = inv_s[p];
#pragma unroll
            for (int nt = 0; nt < 4; ++nt) {
                float v = (acc3[mt][nt][r] - m) * iv * g3v[nt] + be3v[nt];
                mx[nt] = fmaxf(mx[nt], fmaxf(v, 0.f));
            }
        }
#pragma unroll
    for (int nt = 0; nt < 4; ++nt) {
        float m = mx[nt];
        m = fmaxf(m, __shfl_xor(m, 16));
        m = fmaxf(m, __shfl_xor(m, 32));
        if (lane < 16)  // quad==0 lanes cover cols 0..15
            atomicMax(&gmax[b * 256 + ch3[nt]], __float_as_int(m));
    }
}

// ---------------------------------------------------------------------------
// Kernel 3: heads. One wave per batch row (fp32 exact).
// ---------------------------------------------------------------------------
__global__ __launch_bounds__(64) void final_kernel(
    const float* __restrict__ g, const float* __restrict__ js,
    const float* __restrict__ wp, const float* __restrict__ bp,
    const float* __restrict__ gp, const float* __restrict__ bep,
    const float* __restrict__ ws1, const float* __restrict__ bs1,
    const float* __restrict__ ws2, const float* __restrict__ bs2,
    float* __restrict__ out) {
    const int b = blockIdx.x;
    const int c = threadIdx.x;   // 0..63

    // global token = LN(g @ wp + bp) * gp + bep
    const float* grow = g + b * 256;
    float acc = bp[c];
    for (int k = 0; k < 256; ++k) acc = fmaf(grow[k], wp[k * 64 + c], acc);
    float s = acc;
#pragma unroll
    for (int m = 1; m < 64; m <<= 1) s += __shfl_xor(s, m);
    float mean = s * (1.f / 64.f);
    float dc = acc - mean;
    float q = dc * dc;
#pragma unroll
    for (int m = 1; m < 64; m <<= 1) q += __shfl_xor(q, m);
    float var = q * (1.f / 64.f);
    out[b * 128 + c] = dc * rsqrtf(var + EPS) * gp[c] + bep[c];

    // joint-state branch
    const float* jrow = js + b * 32;
    float h = bs1[c];
    for (int k = 0; k < 32; ++k) h = fmaf(jrow[k], ws1[k * 64 + c], h);
    h = fmaxf(h, 0.f);
    float s2 = bs2[c];
    for (int k = 0; k < 64; ++k) s2 = fmaf(__shfl(h, k), ws2[k * 64 + c], s2);
    out[b * 128 + 64 + c] = s2;
}

// ---------------------------------------------------------------------------
extern "C" void kernel_launch(void* const* d_in, const int* in_sizes, int n_in,
                              void* d_out, int out_size, void* d_ws, size_t ws_size,
                              hipStream_t stream) {
    const float* pc  = (const float*)d_in[0];   // (256, 8192, 3)
    const float* js  = (const float*)d_in[1];   // (256, 32)
    // d_in[2] = num_points (2048, fixed by setup — hardcoded)
    const float* w1  = (const float*)d_in[3];
    const float* b1  = (const float*)d_in[4];
    const float* g1  = (const float*)d_in[5];
    const float* be1 = (const float*)d_in[6];
    const float* w2  = (const float*)d_in[7];
    const float* b2  = (const float*)d_in[8];
    const float* g2  = (const float*)d_in[9];
    const float* be2 = (const float*)d_in[10];
    const float* w3  = (const float*)d_in[11];
    const float* b3  = (const float*)d_in[12];
    const float* g3  = (const float*)d_in[13];
    const float* be3 = (const float*)d_in[14];
    const float* wp  = (const float*)d_in[15];
    const float* bp  = (const float*)d_in[16];
    const float* gp  = (const float*)d_in[17];
    const float* bep = (const float*)d_in[18];
    const float* ws1 = (const float*)d_in[19];
    const float* bs1 = (const float*)d_in[20];
    const float* ws2 = (const float*)d_in[21];
    const float* bs2 = (const float*)d_in[22];

    char* ws = (char*)d_ws;
    float* sampled = (float*)(ws + 0);               // 256*2048*3 f32 = 6291456 B
    int*   gmax    = (int*)(ws + 6291456);           // 256*256 i32   =  262144 B
    short* w2T     = (short*)(ws + 6553600);         // 128*64 bf16   =   16384 B
    short* w3T     = (short*)(ws + 6569984);         // 256*128 bf16  =   65536 B

    prep_kernel<<<256, 256, 0, stream>>>(w2, w3, w2T, w3T, gmax);
    fps_kernel<<<256, 256, 0, stream>>>(pc, sampled);
    mlp_kernel<<<8192, 256, 0, stream>>>(sampled, w1, b1, g1, be1,
                                         w2T, b2, g2, be2, w3T, b3, g3, be3, gmax);
    final_kernel<<<256, 64, 0, stream>>>((const float*)gmax, js, wp, bp, gp, bep,
                                         ws1, bs1, ws2, bs2, (float*)d_out);
}

// Round 8
// 2279.826 us; speedup vs baseline: 1.1561x; 1.0043x over previous
//
#include <hip/hip_runtime.h>
#include <hip/hip_bf16.h>

#define EPS 1e-5f

typedef __attribute__((ext_vector_type(8))) short short8;
typedef __attribute__((ext_vector_type(4))) float floatx4;

static __device__ __forceinline__ short f2bf(float f) {
    __hip_bfloat16 h = __float2bfloat16(f);
    return *reinterpret_cast<short*>(&h);
}

// ---------------------------------------------------------------------------
// Kernel 0: prep — transpose+convert w2,w3 to bf16, zero the max-pool buffer
// ---------------------------------------------------------------------------
__global__ __launch_bounds__(256) void prep_kernel(const float* __restrict__ w2,
                                                   const float* __restrict__ w3,
                                                   short* __restrict__ w2T,
                                                   short* __restrict__ w3T,
                                                   int* __restrict__ gmax) {
    int i = blockIdx.x * 256 + threadIdx.x;   // grid 256 -> 65536 threads
    if (i < 8192) {                 // w2: [64][128] -> w2T[128][64]
        int k = i >> 7, n = i & 127;
        w2T[n * 64 + k] = f2bf(w2[i]);
    } else if (i < 40960) {         // w3: [128][256] -> w3T[256][128]
        int j = i - 8192;
        int k = j >> 8, n = j & 255;
        w3T[n * 128 + k] = f2bf(w3[j]);
    }
    if (i < 256 * 256) gmax[i] = 0; // float 0.0f bits
}

// ---------------------------------------------------------------------------
// Kernel 1: farthest point sampling. One block (512 thr = 8 waves, 2 waves
// per SIMD) per batch. 16 points/thread in scalar register arrays (64 array
// VGPRs + temps ~110; __launch_bounds__(512,2) -> 256-VGPR cap, fits).
// R8 A/B vs R7 (256 thr / 32 pt): R7's 132-VGPR alloc couldn't hold the
// 128-reg arrays (compiler demotion suspected) and 1 wave/SIMD ran at
// ~3cyc/instr (latency-exposed). 2 waves/SIMD should saturate issue at
// 2cyc/instr with the arrays truly register-resident. Everything else
// identical to R7: scalar math, atomicMax 3-slot rotation, LDS sout.
// Argmax key: u64 (dist_bits<<32 | 8191-idx); 6-step DPP wave max-reduce;
// lane 63 -> ds_max_u64. ONE barrier/step. Exact fp32, contraction off,
// numpy op order (dx*dx + dy*dy) + dz*dz.
// ---------------------------------------------------------------------------
#define DPP_MAXU64(pk, CTRL, RM)                                             \
    {                                                                        \
        int lo_ = (int)(unsigned)((pk) & 0xffffffffull);                     \
        int hi_ = (int)(unsigned)((pk) >> 32);                               \
        int nlo_ = __builtin_amdgcn_update_dpp(lo_, lo_, CTRL, RM, 0xf, false); \
        int nhi_ = __builtin_amdgcn_update_dpp(hi_, hi_, CTRL, RM, 0xf, false); \
        unsigned long long o_ =                                              \
            ((unsigned long long)(unsigned)nhi_ << 32) | (unsigned)nlo_;     \
        if (o_ > (pk)) (pk) = o_;                                            \
    }

__global__ __launch_bounds__(512, 2) void fps_kernel(const float* __restrict__ pc,
                                                     float* __restrict__ sampled) {
#pragma clang fp contract(off)
    const int b = blockIdx.x;
    const int tid = threadIdx.x;   // 0..511
    const int lane = tid & 63;
    const float* __restrict__ P = pc + (size_t)b * 8192 * 3;
    float* __restrict__ outp = sampled + (size_t)b * 2048 * 3;

    __shared__ float sx[8192];
    __shared__ float sy[8192];
    __shared__ float sz[8192];
    __shared__ float sout[2048 * 3];
    __shared__ unsigned long long slots[3];

    // stage coords: global -> registers and LDS. thread owns points j*512+tid
    float px[16], py[16], pz[16], d[16];
#pragma unroll
    for (int j = 0; j < 16; ++j) {
        int i0 = j * 512 + tid;
        float x0 = P[i0 * 3 + 0], y0 = P[i0 * 3 + 1], z0 = P[i0 * 3 + 2];
        px[j] = x0; py[j] = y0; pz[j] = z0;
        d[j] = INFINITY;
        sx[i0] = x0; sy[i0] = y0; sz[i0] = z0;
    }
    if (tid < 3) slots[tid] = 0ull;
    __syncthreads();

    int far = 0;
    int p = 0;   // = s % 3
    for (int s = 0; s < 2048; ++s) {
        const float cx = sx[far];
        const float cy = sy[far];
        const float cz = sz[far];
        if (tid == 0) {
            sout[s * 3 + 0] = cx;
            sout[s * 3 + 1] = cy;
            sout[s * 3 + 2] = cz;
        }
        if (s == 2047) break;

        float bv = -1.0f;
        int bj = 0;
#pragma unroll
        for (int j = 0; j < 16; ++j) {
            float dx = px[j] - cx;
            float dy = py[j] - cy;
            float dz = pz[j] - cz;
            // exact numpy order: (dx*dx + dy*dy) + dz*dz, contraction OFF
            float dd = (dx * dx + dy * dy) + dz * dz;
            float nd = fminf(d[j], dd);
            d[j] = nd;
            // strict > keeps smallest j on ties -> smallest global index
            bj = (nd > bv) ? j : bj;
            bv = fmaxf(bv, nd);
        }
        int bi = (bj << 9) + tid;   // j*512 + tid

        // pack: max value, then min index (8191-idx grows as idx shrinks)
        unsigned long long pk =
            ((unsigned long long)__float_as_uint(bv) << 32) | (unsigned)(8191 - bi);

        // 6-step DPP wave max-reduce -> lane 63 holds the wave max
        DPP_MAXU64(pk, 0x111, 0xf);  // row_shr:1
        DPP_MAXU64(pk, 0x112, 0xf);  // row_shr:2
        DPP_MAXU64(pk, 0x114, 0xf);  // row_shr:4
        DPP_MAXU64(pk, 0x118, 0xf);  // row_shr:8
        DPP_MAXU64(pk, 0x142, 0xa);  // row_bcast15 -> rows 1,3
        DPP_MAXU64(pk, 0x143, 0xc);  // row_bcast31 -> rows 2,3

        if (lane == 63)
            atomicMax(&slots[p], pk);            // ds_max_u64, 8/step
        __syncthreads();

        unsigned long long best = slots[p];
        if (tid == 0)
            slots[p >= 1 ? p - 1 : 2] = 0ull;    // reset slot for step s+2
        far = 8191 - (int)(unsigned)(best & 0xFFFFFFFFull);
        p = (p == 2) ? 0 : p + 1;
    }

    __syncthreads();
#pragma unroll
    for (int i = 0; i < 12; ++i)
        outp[i * 512 + tid] = sout[i * 512 + tid];
}

// ---------------------------------------------------------------------------
// Kernel 2: fused per-point MLP (3->64->128->256, LN+ReLU each) + max-pool.
// Block = 256 thr (4 waves) handles 64 points of one batch.
// MFMA 16x16x32 bf16; LN stats via per-lane partials + LDS reduce.
// Fragment layouts (m89/m120 verified):
//   A[m][k]: m = lane&15, k = (lane>>4)*8 + j
//   B[k][n]: n = lane&15, k = (lane>>4)*8 + j
//   D[row][col]: col = lane&15, row = (lane>>4)*4 + reg
// ---------------------------------------------------------------------------
__global__ __launch_bounds__(256) void mlp_kernel(
    const float* __restrict__ sampled,
    const float* __restrict__ w1, const float* __restrict__ b1,
    const float* __restrict__ g1, const float* __restrict__ be1,
    const short* __restrict__ w2T, const float* __restrict__ b2,
    const float* __restrict__ g2, const float* __restrict__ be2,
    const short* __restrict__ w3T, const float* __restrict__ b3,
    const float* __restrict__ g3, const float* __restrict__ be3,
    int* __restrict__ gmax) {

    const int b = blockIdx.x >> 5;
    const int chunk = blockIdx.x & 31;
    const int tid = threadIdx.x;
    const int w = tid >> 6;        // wave 0..3
    const int lane = tid & 63;
    const int quad = lane >> 4;
    const int col = lane & 15;

    __shared__ __align__(16) short X1[64 * 72];          //  9216 B bf16 h1
    __shared__ __align__(16) char bufB[64 * 136 * 2];    // 17408 B: Y1(f32) then X2(bf16)
    __shared__ float statsS[64 * 65];                    // 16640 B
    __shared__ float statsQ[64 * 65];                    // 16640 B
    __shared__ float mean_s[64];
    __shared__ float inv_s[64];

    float* Y1 = reinterpret_cast<float*>(bufB);          // [64][65]
    short* X2 = reinterpret_cast<short*>(bufB);          // [64][136]

    // ---- preload B fragments (weights, bf16, transposed layout) ----
    short8 b2f[2][2];
#pragma unroll
    for (int nt = 0; nt < 2; ++nt)
#pragma unroll
        for (int ks = 0; ks < 2; ++ks)
            b2f[nt][ks] = *(const short8*)&w2T[((w * 2 + nt) * 16 + col) * 64 + ks * 32 + quad * 8];
    short8 b3f[4][4];
#pragma unroll
    for (int nt = 0; nt < 4; ++nt)
#pragma unroll
        for (int ks = 0; ks < 4; ++ks)
            b3f[nt][ks] = *(const short8*)&w3T[((w * 4 + nt) * 16 + col) * 128 + ks * 32 + quad * 8];

    // ---- layer 1 (VALU): 3 -> 64 ----
    const int pt = tid & 63;
    const int cg = (tid >> 6) * 16;
    const float* Pp = &sampled[((size_t)b * 2048 + chunk * 64 + pt) * 3];
    const float x = Pp[0], y = Pp[1], z = Pp[2];
#pragma unroll
    for (int c = 0; c < 16; ++c) {
        int ch = cg + c;
        Y1[pt * 65 + ch] = fmaf(x, w1[ch], fmaf(y, w1[64 + ch], fmaf(z, w1[128 + ch], b1[ch])));
    }
    __syncthreads();

    if (tid < 64) {
        float s = 0.f, q = 0.f;
        for (int k = 0; k < 64; ++k) {
            float v = Y1[tid * 65 + k];
            s += v; q += v * v;
        }
        float m = s * (1.f / 64.f);
        float var = q * (1.f / 64.f) - m * m;
        mean_s[tid] = m;
        inv_s[tid] = rsqrtf(var + EPS);
    }
    __syncthreads();

#pragma unroll
    for (int c = 0; c < 16; ++c) {
        int ch = cg + c;
        float v = (Y1[pt * 65 + ch] - mean_s[pt]) * inv_s[pt] * g1[ch] + be1[ch];
        X1[pt * 72 + ch] = f2bf(fmaxf(v, 0.f));
    }
    __syncthreads();

    // ---- layer 2 (MFMA): 64 -> 128 ----
    const floatx4 zf = {0.f, 0.f, 0.f, 0.f};
    floatx4 acc2[4][2];
#pragma unroll
    for (int mt = 0; mt < 4; ++mt) {
        acc2[mt][0] = zf; acc2[mt][1] = zf;
        short8 a[2];
#pragma unroll
        for (int ks = 0; ks < 2; ++ks)
            a[ks] = *(const short8*)&X1[(mt * 16 + col) * 72 + ks * 32 + quad * 8];
#pragma unroll
        for (int nt = 0; nt < 2; ++nt)
#pragma unroll
            for (int ks = 0; ks < 2; ++ks)
                acc2[mt][nt] = __builtin_amdgcn_mfma_f32_16x16x32_bf16(a[ks], b2f[nt][ks], acc2[mt][nt], 0, 0, 0);
    }
    int ch2[2];
    float b2v[2], g2v[2], be2v[2];
#pragma unroll
    for (int nt = 0; nt < 2; ++nt) {
        ch2[nt] = (w * 2 + nt) * 16 + col;
        b2v[nt] = b2[ch2[nt]]; g2v[nt] = g2[ch2[nt]]; be2v[nt] = be2[ch2[nt]];
    }
#pragma unroll
    for (int mt = 0; mt < 4; ++mt)
#pragma unroll
        for (int r = 0; r < 4; ++r) {
            float v0 = acc2[mt][0][r] + b2v[0];
            float v1 = acc2[mt][1][r] + b2v[1];
            acc2[mt][0][r] = v0; acc2[mt][1][r] = v1;
            int p = mt * 16 + quad * 4 + r;
            statsS[p * 65 + w * 16 + col] = v0 + v1;
            statsQ[p * 65 + w * 16 + col] = v0 * v0 + v1 * v1;
        }
    __syncthreads();
    if (tid < 64) {
        float s = 0.f, q = 0.f;
        for (int k = 0; k < 64; ++k) { s += statsS[tid * 65 + k]; q += statsQ[tid * 65 + k]; }
        float m = s * (1.f / 128.f);
        float var = q * (1.f / 128.f) - m * m;
        mean_s[tid] = m;
        inv_s[tid] = rsqrtf(var + EPS);
    }
    __syncthreads();
#pragma unroll
    for (int mt = 0; mt < 4; ++mt)
#pragma unroll
        for (int r = 0; r < 4; ++r) {
            int p = mt * 16 + quad * 4 + r;
            float m = mean_s[p], iv = inv_s[p];
#pragma unroll
            for (int nt = 0; nt < 2; ++nt) {
                float v = (acc2[mt][nt][r] - m) * iv * g2v[nt] + be2v[nt];
                X2[p * 136 + ch2[nt]] = f2bf(fmaxf(v, 0.f));
            }
        }
    __syncthreads();

    // ---- layer 3 (MFMA): 128 -> 256 ----
    floatx4 acc3[4][4];
#pragma unroll
    for (int mt = 0; mt < 4; ++mt) {
#pragma unroll
        for (int nt = 0; nt < 4; ++nt) acc3[mt][nt] = zf;
        short8 a[4];
#pragma unroll
        for (int ks = 0; ks < 4; ++ks)
            a[ks] = *(const short8*)&X2[(mt * 16 + col) * 136 + ks * 32 + quad * 8];
#pragma unroll
        for (int nt = 0; nt < 4; ++nt)
#pragma unroll
            for (int ks = 0; ks < 4; ++ks)
                acc3[mt][nt] = __builtin_amdgcn_mfma_f32_16x16x32_bf16(a[ks], b3f[nt][ks], acc3[mt][nt], 0, 0, 0);
    }
    int ch3[4];
    float b3v[4], g3v[4], be3v[4];
#pragma unroll
    for (int nt = 0; nt < 4; ++nt) {
        ch3[nt] = (w * 4 + nt) * 16 + col;
        b3v[nt] = b3[ch3[nt]]; g3v[nt] = g3[ch3[nt]]; be3v[nt] = be3[ch3[nt]];
    }
#pragma unroll
    for (int mt = 0; mt < 4; ++mt)
#pragma unroll
        for (int r = 0; r < 4; ++r) {
            float s = 0.f, q = 0.f;
#pragma unroll
            for (int nt = 0; nt < 4; ++nt) {
                float v = acc3[mt][nt][r] + b3v[nt];
                acc3[mt][nt][r] = v;
                s += v; q += v * v;
            }
            int p = mt * 16 + quad * 4 + r;
            statsS[p * 65 + w * 16 + col] = s;
            statsQ[p * 65 + w * 16 + col] = q;
        }
    __syncthreads();
    if (tid < 64) {
        float s = 0.f, q = 0.f;
        for (int k = 0; k < 64; ++k) { s += statsS[tid * 65 + k]; q += statsQ[tid * 65 + k]; }
        float m = s * (1.f / 256.f);
        float var = q * (1.f / 256.f) - m * m;
        mean_s[tid] = m;
        inv_s[tid] = rsqrtf(var + EPS);
    }
    __syncthreads();

    // ---- LN3 + ReLU + max over the block's 64 points ----
    float mx[4] = {0.f, 0.f, 0.f, 0.f};
#pragma unroll
    for (int mt = 0; mt < 4; ++mt)
#pragma unroll
        for (int r = 0; r < 4; ++r) {
            int p = mt * 16 + quad * 4 + r;
            float m = mean_s[p], iv = inv_s[p];
#pragma unroll
            for (int nt = 0; nt < 4; ++nt) {
                float v = (acc3[mt][nt][r] - m) * iv * g3v[nt] + be3v[nt];
                mx[nt] = fmaxf(mx[nt], fmaxf(v, 0.f));
            }
        }
#pragma unroll
    for (int nt = 0; nt < 4; ++nt) {
        float m = mx[nt];
        m = fmaxf(m, __shfl_xor(m, 16));
        m = fmaxf(m, __shfl_xor(m, 32));
        if (lane < 16)  // quad==0 lanes cover cols 0..15
            atomicMax(&gmax[b * 256 + ch3[nt]], __float_as_int(m));
    }
}

// ---------------------------------------------------------------------------
// Kernel 3: heads. One wave per batch row (fp32 exact).
// ---------------------------------------------------------------------------
__global__ __launch_bounds__(64) void final_kernel(
    const float* __restrict__ g, const float* __restrict__ js,
    const float* __restrict__ wp, const float* __restrict__ bp,
    const float* __restrict__ gp, const float* __restrict__ bep,
    const float* __restrict__ ws1, const float* __restrict__ bs1,
    const float* __restrict__ ws2, const float* __restrict__ bs2,
    float* __restrict__ out) {
    const int b = blockIdx.x;
    const int c = threadIdx.x;   // 0..63

    // global token = LN(g @ wp + bp) * gp + bep
    const float* grow = g + b * 256;
    float acc = bp[c];
    for (int k = 0; k < 256; ++k) acc = fmaf(grow[k], wp[k * 64 + c], acc);
    float s = acc;
#pragma unroll
    for (int m = 1; m < 64; m <<= 1) s += __shfl_xor(s, m);
    float mean = s * (1.f / 64.f);
    float dc = acc - mean;
    float q = dc * dc;
#pragma unroll
    for (int m = 1; m < 64; m <<= 1) q += __shfl_xor(q, m);
    float var = q * (1.f / 64.f);
    out[b * 128 + c] = dc * rsqrtf(var + EPS) * gp[c] + bep[c];

    // joint-state branch
    const float* jrow = js + b * 32;
    float h = bs1[c];
    for (int k = 0; k < 32; ++k) h = fmaf(jrow[k], ws1[k * 64 + c], h);
    h = fmaxf(h, 0.f);
    float s2 = bs2[c];
    for (int k = 0; k < 64; ++k) s2 = fmaf(__shfl(h, k), ws2[k * 64 + c], s2);
    out[b * 128 + 64 + c] = s2;
}

// ---------------------------------------------------------------------------
extern "C" void kernel_launch(void* const* d_in, const int* in_sizes, int n_in,
                              void* d_out, int out_size, void* d_ws, size_t ws_size,
                              hipStream_t stream) {
    const float* pc  = (const float*)d_in[0];   // (256, 8192, 3)
    const float* js  = (const float*)d_in[1];   // (256, 32)
    // d_in[2] = num_points (2048, fixed by setup — hardcoded)
    const float* w1  = (const float*)d_in[3];
    const float* b1  = (const float*)d_in[4];
    const float* g1  = (const float*)d_in[5];
    const float* be1 = (const float*)d_in[6];
    const float* w2  = (const float*)d_in[7];
    const float* b2  = (const float*)d_in[8];
    const float* g2  = (const float*)d_in[9];
    const float* be2 = (const float*)d_in[10];
    const float* w3  = (const float*)d_in[11];
    const float* b3  = (const float*)d_in[12];
    const float* g3  = (const float*)d_in[13];
    const float* be3 = (const float*)d_in[14];
    const float* wp  = (const float*)d_in[15];
    const float* bp  = (const float*)d_in[16];
    const float* gp  = (const float*)d_in[17];
    const float* bep = (const float*)d_in[18];
    const float* ws1 = (const float*)d_in[19];
    const float* bs1 = (const float*)d_in[20];
    const float* ws2 = (const float*)d_in[21];
    const float* bs2 = (const float*)d_in[22];

    char* ws = (char*)d_ws;
    float* sampled = (float*)(ws + 0);               // 256*2048*3 f32 = 6291456 B
    int*   gmax    = (int*)(ws + 6291456);           // 256*256 i32   =  262144 B
    short* w2T     = (short*)(ws + 6553600);         // 128*64 bf16   =   16384 B
    short* w3T     = (short*)(ws + 6569984);         // 256*128 bf16  =   65536 B

    prep_kernel<<<256, 256, 0, stream>>>(w2, w3, w2T, w3T, gmax);
    fps_kernel<<<256, 512, 0, stream>>>(pc, sampled);
    mlp_kernel<<<8192, 256, 0, stream>>>(sampled, w1, b1, g1, be1,
                                         w2T, b2, g2, be2, w3T, b3, g3, be3, gmax);
    final_kernel<<<256, 64, 0, stream>>>((const float*)gmax, js, wp, bp, gp, bep,
                                         ws1, bs1, ws2, bs2, (float*)d_out);
}

// Round 9
// 2082.554 us; speedup vs baseline: 1.2657x; 1.0947x over previous
//
#include <hip/hip_runtime.h>
#include <hip/hip_bf16.h>

#define EPS 1e-5f

typedef __attribute__((ext_vector_type(8))) short short8;
typedef __attribute__((ext_vector_type(4))) float floatx4;

static __device__ __forceinline__ short f2bf(float f) {
    __hip_bfloat16 h = __float2bfloat16(f);
    return *reinterpret_cast<short*>(&h);
}

// ---------------------------------------------------------------------------
// Kernel 0: prep — transpose+convert w2,w3 to bf16, zero the max-pool buffer
// ---------------------------------------------------------------------------
__global__ __launch_bounds__(256) void prep_kernel(const float* __restrict__ w2,
                                                   const float* __restrict__ w3,
                                                   short* __restrict__ w2T,
                                                   short* __restrict__ w3T,
                                                   int* __restrict__ gmax) {
    int i = blockIdx.x * 256 + threadIdx.x;   // grid 256 -> 65536 threads
    if (i < 8192) {                 // w2: [64][128] -> w2T[128][64]
        int k = i >> 7, n = i & 127;
        w2T[n * 64 + k] = f2bf(w2[i]);
    } else if (i < 40960) {         // w3: [128][256] -> w3T[256][128]
        int j = i - 8192;
        int k = j >> 8, n = j & 255;
        w3T[n * 128 + k] = f2bf(w3[j]);
    }
    if (i < 256 * 256) gmax[i] = 0; // float 0.0f bits
}

// ---------------------------------------------------------------------------
// Kernel 1: farthest point sampling. One block (512 thr = 8 waves) per batch.
// 16 points/thread in scalar register arrays. R9: wave argmax split into
// (a) 32-bit value-only DPP max (dist>=0 -> fp32 bits u32-monotone; 6 steps
// of dpp+v_max_u32, half the chain of the old u64 butterfly), then
// (b) index resolution via readlane(63) -> ballot(tie) -> readlane(ffs):
// all SGPR ops, no second reduce. Multi-tie handled by wave-uniform scalar
// min loop (rare, still exact). Cross-wave: u64 (value<<32 | 8191-idx)
// ds atomicMax keeps global first-index argmax bit-identical to jnp.argmax.
// ONE barrier/step; 3-slot rotating cell; exact fp32, contraction off,
// numpy op order (dx*dx + dy*dy) + dz*dz.
// ---------------------------------------------------------------------------
#define DPP_MAXU32(v, CTRL, RM)                                              \
    {                                                                        \
        int t_ = __builtin_amdgcn_update_dpp((int)(v), (int)(v), CTRL, RM, 0xf, false); \
        (v) = ((unsigned)t_ > (v)) ? (unsigned)t_ : (v);                     \
    }

__global__ __launch_bounds__(512, 2) void fps_kernel(const float* __restrict__ pc,
                                                     float* __restrict__ sampled) {
#pragma clang fp contract(off)
    const int b = blockIdx.x;
    const int tid = threadIdx.x;   // 0..511
    const int lane = tid & 63;
    const float* __restrict__ P = pc + (size_t)b * 8192 * 3;
    float* __restrict__ outp = sampled + (size_t)b * 2048 * 3;

    __shared__ float sx[8192];
    __shared__ float sy[8192];
    __shared__ float sz[8192];
    __shared__ float sout[2048 * 3];
    __shared__ unsigned long long slots[3];

    // stage coords: global -> registers and LDS. thread owns points j*512+tid
    float px[16], py[16], pz[16], d[16];
#pragma unroll
    for (int j = 0; j < 16; ++j) {
        int i0 = j * 512 + tid;
        float x0 = P[i0 * 3 + 0], y0 = P[i0 * 3 + 1], z0 = P[i0 * 3 + 2];
        px[j] = x0; py[j] = y0; pz[j] = z0;
        d[j] = INFINITY;
        sx[i0] = x0; sy[i0] = y0; sz[i0] = z0;
    }
    if (tid < 3) slots[tid] = 0ull;
    __syncthreads();

    int far = 0;
    int p = 0;   // = s % 3
    for (int s = 0; s < 2048; ++s) {
        const float cx = sx[far];
        const float cy = sy[far];
        const float cz = sz[far];
        if (tid == 0) {
            sout[s * 3 + 0] = cx;
            sout[s * 3 + 1] = cy;
            sout[s * 3 + 2] = cz;
        }
        if (s == 2047) break;

        float bv = -1.0f;
        int bj = 0;
#pragma unroll
        for (int j = 0; j < 16; ++j) {
            float dx = px[j] - cx;
            float dy = py[j] - cy;
            float dz = pz[j] - cz;
            // exact numpy order: (dx*dx + dy*dy) + dz*dz, contraction OFF
            float dd = (dx * dx + dy * dy) + dz * dz;
            float nd = fminf(d[j], dd);
            d[j] = nd;
            // strict > keeps smallest j on ties -> smallest global index
            bj = (nd > bv) ? j : bj;
            bv = fmaxf(bv, nd);
        }
        int bi = (bj << 9) + tid;   // j*512 + tid

        // ---- wave argmax, value-only 32-bit DPP reduce ----
        unsigned v = __float_as_uint(bv);   // dist >= 0 -> u32 monotone
        DPP_MAXU32(v, 0x111, 0xf);  // row_shr:1
        DPP_MAXU32(v, 0x112, 0xf);  // row_shr:2
        DPP_MAXU32(v, 0x114, 0xf);  // row_shr:4
        DPP_MAXU32(v, 0x118, 0xf);  // row_shr:8
        DPP_MAXU32(v, 0x142, 0xa);  // row_bcast15 -> rows 1,3
        DPP_MAXU32(v, 0x143, 0xc);  // row_bcast31 -> rows 2,3

        // lane 63 holds wave max; broadcast via readlane (SGPR)
        unsigned wmax = (unsigned)__builtin_amdgcn_readlane((int)v, 63);
        unsigned long long tied = __ballot(__float_as_uint(bv) == wmax);
        int fl = __ffsll(tied) - 1;
        int widx = __builtin_amdgcn_readlane(bi, fl);
        if (__popcll(tied) > 1) {           // rare; wave-uniform scalar path
            unsigned long long m = tied & (tied - 1);
            while (m) {
                int l = __ffsll(m) - 1;
                int c = __builtin_amdgcn_readlane(bi, l);
                widx = (c < widx) ? c : widx;
                m &= m - 1;
            }
        }

        if (lane == 0)
            atomicMax(&slots[p],
                      ((unsigned long long)wmax << 32) | (unsigned)(8191 - widx));
        __syncthreads();

        unsigned long long best = slots[p];
        if (tid == 0)
            slots[p >= 1 ? p - 1 : 2] = 0ull;    // reset slot for step s+2
        far = 8191 - (int)(unsigned)(best & 0xFFFFFFFFull);
        p = (p == 2) ? 0 : p + 1;
    }

    __syncthreads();
#pragma unroll
    for (int i = 0; i < 12; ++i)
        outp[i * 512 + tid] = sout[i * 512 + tid];
}

// ---------------------------------------------------------------------------
// Kernel 2: fused per-point MLP (3->64->128->256, LN+ReLU each) + max-pool.
// Block = 256 thr (4 waves) handles 64 points of one batch.
// MFMA 16x16x32 bf16; LN stats via per-lane partials + LDS reduce.
// Fragment layouts (m89/m120 verified):
//   A[m][k]: m = lane&15, k = (lane>>4)*8 + j
//   B[k][n]: n = lane&15, k = (lane>>4)*8 + j
//   D[row][col]: col = lane&15, row = (lane>>4)*4 + reg
// ---------------------------------------------------------------------------
__global__ __launch_bounds__(256) void mlp_kernel(
    const float* __restrict__ sampled,
    const float* __restrict__ w1, const float* __restrict__ b1,
    const float* __restrict__ g1, const float* __restrict__ be1,
    const short* __restrict__ w2T, const float* __restrict__ b2,
    const float* __restrict__ g2, const float* __restrict__ be2,
    const short* __restrict__ w3T, const float* __restrict__ b3,
    const float* __restrict__ g3, const float* __restrict__ be3,
    int* __restrict__ gmax) {

    const int b = blockIdx.x >> 5;
    const int chunk = blockIdx.x & 31;
    const int tid = threadIdx.x;
    const int w = tid >> 6;        // wave 0..3
    const int lane = tid & 63;
    const int quad = lane >> 4;
    const int col = lane & 15;

    __shared__ __align__(16) short X1[64 * 72];          //  9216 B bf16 h1
    __shared__ __align__(16) char bufB[64 * 136 * 2];    // 17408 B: Y1(f32) then X2(bf16)
    __shared__ float statsS[64 * 65];                    // 16640 B
    __shared__ float statsQ[64 * 65];                    // 16640 B
    __shared__ float mean_s[64];
    __shared__ float inv_s[64];

    float* Y1 = reinterpret_cast<float*>(bufB);          // [64][65]
    short* X2 = reinterpret_cast<short*>(bufB);          // [64][136]

    // ---- preload B fragments (weights, bf16, transposed layout) ----
    short8 b2f[2][2];
#pragma unroll
    for (int nt = 0; nt < 2; ++nt)
#pragma unroll
        for (int ks = 0; ks < 2; ++ks)
            b2f[nt][ks] = *(const short8*)&w2T[((w * 2 + nt) * 16 + col) * 64 + ks * 32 + quad * 8];
    short8 b3f[4][4];
#pragma unroll
    for (int nt = 0; nt < 4; ++nt)
#pragma unroll
        for (int ks = 0; ks < 4; ++ks)
            b3f[nt][ks] = *(const short8*)&w3T[((w * 4 + nt) * 16 + col) * 128 + ks * 32 + quad * 8];

    // ---- layer 1 (VALU): 3 -> 64 ----
    const int pt = tid & 63;
    const int cg = (tid >> 6) * 16;
    const float* Pp = &sampled[((size_t)b * 2048 + chunk * 64 + pt) * 3];
    const float x = Pp[0], y = Pp[1], z = Pp[2];
#pragma unroll
    for (int c = 0; c < 16; ++c) {
        int ch = cg + c;
        Y1[pt * 65 + ch] = fmaf(x, w1[ch], fmaf(y, w1[64 + ch], fmaf(z, w1[128 + ch], b1[ch])));
    }
    __syncthreads();

    if (tid < 64) {
        float s = 0.f, q = 0.f;
        for (int k = 0; k < 64; ++k) {
            float v = Y1[tid * 65 + k];
            s += v; q += v * v;
        }
        float m = s * (1.f / 64.f);
        float var = q * (1.f / 64.f) - m * m;
        mean_s[tid] = m;
        inv_s[tid] = rsqrtf(var + EPS);
    }
    __syncthreads();

#pragma unroll
    for (int c = 0; c < 16; ++c) {
        int ch = cg + c;
        float v = (Y1[pt * 65 + ch] - mean_s[pt]) * inv_s[pt] * g1[ch] + be1[ch];
        X1[pt * 72 + ch] = f2bf(fmaxf(v, 0.f));
    }
    __syncthreads();

    // ---- layer 2 (MFMA): 64 -> 128 ----
    const floatx4 zf = {0.f, 0.f, 0.f, 0.f};
    floatx4 acc2[4][2];
#pragma unroll
    for (int mt = 0; mt < 4; ++mt) {
        acc2[mt][0] = zf; acc2[mt][1] = zf;
        short8 a[2];
#pragma unroll
        for (int ks = 0; ks < 2; ++ks)
            a[ks] = *(const short8*)&X1[(mt * 16 + col) * 72 + ks * 32 + quad * 8];
#pragma unroll
        for (int nt = 0; nt < 2; ++nt)
#pragma unroll
            for (int ks = 0; ks < 2; ++ks)
                acc2[mt][nt] = __builtin_amdgcn_mfma_f32_16x16x32_bf16(a[ks], b2f[nt][ks], acc2[mt][nt], 0, 0, 0);
    }
    int ch2[2];
    float b2v[2], g2v[2], be2v[2];
#pragma unroll
    for (int nt = 0; nt < 2; ++nt) {
        ch2[nt] = (w * 2 + nt) * 16 + col;
        b2v[nt] = b2[ch2[nt]]; g2v[nt] = g2[ch2[nt]]; be2v[nt] = be2[ch2[nt]];
    }
#pragma unroll
    for (int mt = 0; mt < 4; ++mt)
#pragma unroll
        for (int r = 0; r < 4; ++r) {
            float v0 = acc2[mt][0][r] + b2v[0];
            float v1 = acc2[mt][1][r] + b2v[1];
            acc2[mt][0][r] = v0; acc2[mt][1][r] = v1;
            int p = mt * 16 + quad * 4 + r;
            statsS[p * 65 + w * 16 + col] = v0 + v1;
            statsQ[p * 65 + w * 16 + col] = v0 * v0 + v1 * v1;
        }
    __syncthreads();
    if (tid < 64) {
        float s = 0.f, q = 0.f;
        for (int k = 0; k < 64; ++k) { s += statsS[tid * 65 + k]; q += statsQ[tid * 65 + k]; }
        float m = s * (1.f / 128.f);
        float var = q * (1.f / 128.f) - m * m;
        mean_s[tid] = m;
        inv_s[tid] = rsqrtf(var + EPS);
    }
    __syncthreads();
#pragma unroll
    for (int mt = 0; mt < 4; ++mt)
#pragma unroll
        for (int r = 0; r < 4; ++r) {
            int p = mt * 16 + quad * 4 + r;
            float m = mean_s[p], iv = inv_s[p];
#pragma unroll
            for (int nt = 0; nt < 2; ++nt) {
                float v = (acc2[mt][nt][r] - m) * iv * g2v[nt] + be2v[nt];
                X2[p * 136 + ch2[nt]] = f2bf(fmaxf(v, 0.f));
            }
        }
    __syncthreads();

    // ---- layer 3 (MFMA): 128 -> 256 ----
    floatx4 acc3[4][4];
#pragma unroll
    for (int mt = 0; mt < 4; ++mt) {
#pragma unroll
        for (int nt = 0; nt < 4; ++nt) acc3[mt][nt] = zf;
        short8 a[4];
#pragma unroll
        for (int ks = 0; ks < 4; ++ks)
            a[ks] = *(const short8*)&X2[(mt * 16 + col) * 136 + ks * 32 + quad * 8];
#pragma unroll
        for (int nt = 0; nt < 4; ++nt)
#pragma unroll
            for (int ks = 0; ks < 4; ++ks)
                acc3[mt][nt] = __builtin_amdgcn_mfma_f32_16x16x32_bf16(a[ks], b3f[nt][ks], acc3[mt][nt], 0, 0, 0);
    }
    int ch3[4];
    float b3v[4], g3v[4], be3v[4];
#pragma unroll
    for (int nt = 0; nt < 4; ++nt) {
        ch3[nt] = (w * 4 + nt) * 16 + col;
        b3v[nt] = b3[ch3[nt]]; g3v[nt] = g3[ch3[nt]]; be3v[nt] = be3[ch3[nt]];
    }
#pragma unroll
    for (int mt = 0; mt < 4; ++mt)
#pragma unroll
        for (int r = 0; r < 4; ++r) {
            float s = 0.f, q = 0.f;
#pragma unroll
            for (int nt = 0; nt < 4; ++nt) {
                float v = acc3[mt][nt][r] + b3v[nt];
                acc3[mt][nt][r] = v;
                s += v; q += v * v;
            }
            int p = mt * 16 + quad * 4 + r;
            statsS[p * 65 + w * 16 + col] = s;
            statsQ[p * 65 + w * 16 + col] = q;
        }
    __syncthreads();
    if (tid < 64) {
        float s = 0.f, q = 0.f;
        for (int k = 0; k < 64; ++k) { s += statsS[tid * 65 + k]; q += statsQ[tid * 65 + k]; }
        float m = s * (1.f / 256.f);
        float var = q * (1.f / 256.f) - m * m;
        mean_s[tid] = m;
        inv_s[tid] = rsqrtf(var + EPS);
    }
    __syncthreads();

    // ---- LN3 + ReLU + max over the block's 64 points ----
    float mx[4] = {0.f, 0.f, 0.f, 0.f};
#pragma unroll
    for (int mt = 0; mt < 4; ++mt)
#pragma unroll
        for (int r = 0; r < 4; ++r) {
            int p = mt * 16 + quad * 4 + r;
            float m = mean_s[p], iv = inv_s[p];
#pragma unroll
            for (int nt = 0; nt < 4; ++nt) {
                float v = (acc3[mt][nt][r] - m) * iv * g3v[nt] + be3v[nt];
                mx[nt] = fmaxf(mx[nt], fmaxf(v, 0.f));
            }
        }
#pragma unroll
    for (int nt = 0; nt < 4; ++nt) {
        float m = mx[nt];
        m = fmaxf(m, __shfl_xor(m, 16));
        m = fmaxf(m, __shfl_xor(m, 32));
        if (lane < 16)  // quad==0 lanes cover cols 0..15
            atomicMax(&gmax[b * 256 + ch3[nt]], __float_as_int(m));
    }
}

// ---------------------------------------------------------------------------
// Kernel 3: heads. One wave per batch row (fp32 exact).
// ---------------------------------------------------------------------------
__global__ __launch_bounds__(64) void final_kernel(
    const float* __restrict__ g, const float* __restrict__ js,
    const float* __restrict__ wp, const float* __restrict__ bp,
    const float* __restrict__ gp, const float* __restrict__ bep,
    const float* __restrict__ ws1, const float* __restrict__ bs1,
    const float* __restrict__ ws2, const float* __restrict__ bs2,
    float* __restrict__ out) {
    const int b = blockIdx.x;
    const int c = threadIdx.x;   // 0..63

    // global token = LN(g @ wp + bp) * gp + bep
    const float* grow = g + b * 256;
    float acc = bp[c];
    for (int k = 0; k < 256; ++k) acc = fmaf(grow[k], wp[k * 64 + c], acc);
    float s = acc;
#pragma unroll
    for (int m = 1; m < 64; m <<= 1) s += __shfl_xor(s, m);
    float mean = s * (1.f / 64.f);
    float dc = acc - mean;
    float q = dc * dc;
#pragma unroll
    for (int m = 1; m < 64; m <<= 1) q += __shfl_xor(q, m);
    float var = q * (1.f / 64.f);
    out[b * 128 + c] = dc * rsqrtf(var + EPS) * gp[c] + bep[c];

    // joint-state branch
    const float* jrow = js + b * 32;
    float h = bs1[c];
    for (int k = 0; k < 32; ++k) h = fmaf(jrow[k], ws1[k * 64 + c], h);
    h = fmaxf(h, 0.f);
    float s2 = bs2[c];
    for (int k = 0; k < 64; ++k) s2 = fmaf(__shfl(h, k), ws2[k * 64 + c], s2);
    out[b * 128 + 64 + c] = s2;
}

// ---------------------------------------------------------------------------
extern "C" void kernel_launch(void* const* d_in, const int* in_sizes, int n_in,
                              void* d_out, int out_size, void* d_ws, size_t ws_size,
                              hipStream_t stream) {
    const float* pc  = (const float*)d_in[0];   // (256, 8192, 3)
    const float* js  = (const float*)d_in[1];   // (256, 32)
    // d_in[2] = num_points (2048, fixed by setup — hardcoded)
    const float* w1  = (const float*)d_in[3];
    const float* b1  = (const float*)d_in[4];
    const float* g1  = (const float*)d_in[5];
    const float* be1 = (const float*)d_in[6];
    const float* w2  = (const float*)d_in[7];
    const float* b2  = (const float*)d_in[8];
    const float* g2  = (const float*)d_in[9];
    const float* be2 = (const float*)d_in[10];
    const float* w3  = (const float*)d_in[11];
    const float* b3  = (const float*)d_in[12];
    const float* g3  = (const float*)d_in[13];
    const float* be3 = (const float*)d_in[14];
    const float* wp  = (const float*)d_in[15];
    const float* bp  = (const float*)d_in[16];
    const float* gp  = (const float*)d_in[17];
    const float* bep = (const float*)d_in[18];
    const float* ws1 = (const float*)d_in[19];
    const float* bs1 = (const float*)d_in[20];
    const float* ws2 = (const float*)d_in[21];
    const float* bs2 = (const float*)d_in[22];

    char* ws = (char*)d_ws;
    float* sampled = (float*)(ws + 0);               // 256*2048*3 f32 = 6291456 B
    int*   gmax    = (int*)(ws + 6291456);           // 256*256 i32   =  262144 B
    short* w2T     = (short*)(ws + 6553600);         // 128*64 bf16   =   16384 B
    short* w3T     = (short*)(ws + 6569984);         // 256*128 bf16  =   65536 B

    prep_kernel<<<256, 256, 0, stream>>>(w2, w3, w2T, w3T, gmax);
    fps_kernel<<<256, 512, 0, stream>>>(pc, sampled);
    mlp_kernel<<<8192, 256, 0, stream>>>(sampled, w1, b1, g1, be1,
                                         w2T, b2, g2, be2, w3T, b3, g3, be3, gmax);
    final_kernel<<<256, 64, 0, stream>>>((const float*)gmax, js, wp, bp, gp, bep,
                                         ws1, bs1, ws2, bs2, (float*)d_out);
}